// Round 2
// baseline (2132.703 us; speedup 1.0000x reference)
//
#include <hip/hip_runtime.h>
#include <cstdint>

// GAT: N=50000 nodes, E=800000 edges, 128 -> 3 heads x 64, 2 layers, 10 classes
constexpr int KIN = 128;   // NDIM_IN
constexpr int HD  = 192;   // H * NDIM_OUT
constexpr int NC  = 10;    // CLASS_NUM
#define NEG_SLOPE 0.2f

__device__ __forceinline__ float b2f(unsigned short u) {
    union { unsigned int i; float f; } x; x.i = ((unsigned int)u) << 16; return x.f;
}
__device__ __forceinline__ unsigned short f2b(float f) {
    union { float f; unsigned int i; } x; x.f = f;
    unsigned int r = x.i + 0x7FFFu + ((x.i >> 16) & 1u);   // RNE
    return (unsigned short)(r >> 16);
}
// dtype-polymorphic load/store: isbf=1 -> data is bf16 bits, else fp32
__device__ __forceinline__ float gload(const void* p, long i, int isbf) {
    return isbf ? b2f(((const unsigned short*)p)[i]) : ((const float*)p)[i];
}
__device__ __forceinline__ void gstore(void* p, long i, float v, int isbf) {
    if (isbf) ((unsigned short*)p)[i] = f2b(v);
    else      ((float*)p)[i] = v;
}
__device__ __forceinline__ float lrelu(float v) { return v > 0.f ? v : NEG_SLOPE * v; }

// ---- dtype probe: bf16 interp of fp32 data blows up on random low halves ----
__global__ void k_probe(const void* W, int* flag) {
    if (threadIdx.x != 0 || blockIdx.x != 0) return;
    const unsigned short* u = (const unsigned short*)W;
    float mx = 0.f;
    for (int i = 0; i < 64; ++i) {
        float v = fabsf(b2f(u[i]));
        if (!(v < 1e30f)) v = 1e30f;   // NaN/inf -> huge
        mx = fmaxf(mx, v);
    }
    *flag = (mx < 1e4f) ? 1 : 0;       // 1 = bf16, 0 = fp32
}

__global__ void k_zero(int* p, int n) {
    int i = blockIdx.x * blockDim.x + threadIdx.x;
    if (i < n) p[i] = 0;
}

// ---------------- CSR build ----------------
__global__ void k_hist(const int* __restrict__ dst, int E, int* __restrict__ deg) {
    int i = blockIdx.x * blockDim.x + threadIdx.x;
    if (i < E) atomicAdd(&deg[dst[i]], 1);
}

__global__ void k_scan(const int* __restrict__ deg, int n, int* __restrict__ off, int* __restrict__ cur) {
    __shared__ int sh[1024];
    __shared__ int carrysh;
    int tid = threadIdx.x;
    if (tid == 0) carrysh = 0;
    __syncthreads();
    for (int base = 0; base < n; base += 1024) {
        int i = base + tid;
        int v = (i < n) ? deg[i] : 0;
        sh[tid] = v;
        __syncthreads();
        for (int s = 1; s < 1024; s <<= 1) {
            int t = (tid >= s) ? sh[tid - s] : 0;
            __syncthreads();
            sh[tid] += t;
            __syncthreads();
        }
        if (i < n) {
            int excl = carrysh + sh[tid] - v;
            off[i] = excl;
            cur[i] = excl;
        }
        __syncthreads();
        if (tid == 0) carrysh += sh[1023];
        __syncthreads();
    }
    if (tid == 0) off[n] = carrysh;
}

__global__ void k_fill(const int* __restrict__ src, const int* __restrict__ dst, int E,
                       int* __restrict__ cur, int* __restrict__ csr) {
    int i = blockIdx.x * blockDim.x + threadIdx.x;
    if (i < E) {
        int p = atomicAdd(&cur[dst[i]], 1);
        csr[p] = src[i];
    }
}

// ---------- dense projection: out[n,c] = sum_k X[n,k]*W[k,c]; out always fp32 ----------
// mode: 1 = X is harness input; 0/2 = X internal fp32; 3 = X internal fp32 AND W offset by HD*NC elems
__global__ void k_gemm(const void* __restrict__ X, const void* __restrict__ W,
                       float* __restrict__ out, int M, int K, int C,
                       const int* __restrict__ flag, int mode) {
    int t = blockIdx.x * blockDim.x + threadIdx.x;
    if (t >= M * C) return;
    int isb = *flag;
    int xb = (mode == 1) ? isb : 0;
    long woff = (mode == 3) ? (long)HD * NC : 0;
    int n = t / C, c = t % C;
    float acc = 0.f;
    for (int k = 0; k < K; ++k)
        acc += gload(X, (long)n * K + k, xb) * gload(W, woff + (long)k * C + c, isb);
    out[t] = acc;
}

// ---------- el/er per node; f internal fp32; al/ar harness inputs ----------
__global__ void k_elr(const float* __restrict__ f, const void* __restrict__ al,
                      const void* __restrict__ ar, float* __restrict__ el4,
                      float* __restrict__ er4, int Nn, const int* __restrict__ flag) {
    int n = blockIdx.x;
    if (n >= Nn) return;
    int isb = *flag;
    int j = threadIdx.x;      // 0..191
    float fv = f[(long)n * HD + j];
    float e_l = fv * gload(al, j, isb);
    float e_r = fv * gload(ar, j, isb);
    for (int d = 1; d < 64; d <<= 1) {
        e_l += __shfl_xor(e_l, d);
        e_r += __shfl_xor(e_r, d);
    }
    if ((j & 63) == 0) {
        int h = j >> 6;
        el4[n * 4 + h] = e_l;
        er4[n * 4 + h] = e_r;
    }
}

// ---------- softmax + aggregation, one wave per node; out internal fp32 ----------
__global__ void k_agg(const float* __restrict__ f, const float4* __restrict__ el4,
                      const float* __restrict__ er4, const int* __restrict__ off,
                      const int* __restrict__ csr, const void* __restrict__ bias,
                      float* __restrict__ out, int Nn, const int* __restrict__ flag) {
    int lane = threadIdx.x & 63;
    int n = blockIdx.x * (blockDim.x >> 6) + (threadIdx.x >> 6);
    if (n >= Nn) return;
    int isb = *flag;
    int s0 = off[n], s1 = off[n + 1];
    float er0 = er4[n * 4 + 0], er1 = er4[n * 4 + 1], er2 = er4[n * 4 + 2];

    float m0 = -1e30f, m1 = -1e30f, m2 = -1e30f;
    for (int e = s0 + lane; e < s1; e += 64) {
        float4 el = el4[csr[e]];
        m0 = fmaxf(m0, lrelu(el.x + er0));
        m1 = fmaxf(m1, lrelu(el.y + er1));
        m2 = fmaxf(m2, lrelu(el.z + er2));
    }
    for (int d = 1; d < 64; d <<= 1) {
        m0 = fmaxf(m0, __shfl_xor(m0, d));
        m1 = fmaxf(m1, __shfl_xor(m1, d));
        m2 = fmaxf(m2, __shfl_xor(m2, d));
    }
    float d0 = 0.f, d1 = 0.f, d2 = 0.f;
    for (int e = s0 + lane; e < s1; e += 64) {
        float4 el = el4[csr[e]];
        d0 += __expf(lrelu(el.x + er0) - m0);
        d1 += __expf(lrelu(el.y + er1) - m1);
        d2 += __expf(lrelu(el.z + er2) - m2);
    }
    for (int d = 1; d < 64; d <<= 1) {
        d0 += __shfl_xor(d0, d);
        d1 += __shfl_xor(d1, d);
        d2 += __shfl_xor(d2, d);
    }
    float id0 = 1.f / d0, id1 = 1.f / d1, id2 = 1.f / d2;

    float a0 = 0.f, a1 = 0.f, a2 = 0.f;
    for (int e = s0; e < s1; ++e) {
        int s = csr[e];
        float4 el = el4[s];
        float w0 = __expf(lrelu(el.x + er0) - m0) * id0;
        float w1 = __expf(lrelu(el.y + er1) - m1) * id1;
        float w2 = __expf(lrelu(el.z + er2) - m2) * id2;
        const float* fr = f + (long)s * HD;
        a0 += w0 * fr[lane];
        a1 += w1 * fr[lane + 64];
        a2 += w2 * fr[lane + 128];
    }
    a0 = fmaxf(a0 + gload(bias, lane,       isb), 0.f);
    a1 = fmaxf(a1 + gload(bias, lane + 64,  isb), 0.f);
    a2 = fmaxf(a2 + gload(bias, lane + 128, isb), 0.f);
    float* orow = out + (long)n * HD;
    orow[lane]       = a0;
    orow[lane + 64]  = a1;
    orow[lane + 128] = a2;
}

// ---------- per-edge score: out[e,c] = P[src,c] + Q[dst,c] + bp[c] ----------
__global__ void k_score(const int* __restrict__ src, const int* __restrict__ dst,
                        const float* __restrict__ P, const float* __restrict__ Q,
                        const void* __restrict__ bp, void* __restrict__ out,
                        int E, const int* __restrict__ flag) {
    int t = blockIdx.x * blockDim.x + threadIdx.x;
    if (t >= E * NC) return;
    int isb = *flag;
    int e = t / NC, c = t % NC;
    float v = P[src[e] * NC + c] + Q[dst[e] * NC + c] + gload(bp, c, isb);
    gstore(out, t, v, isb);
}

extern "C" void kernel_launch(void* const* d_in, const int* in_sizes, int n_in,
                              void* d_out, int out_size, void* d_ws, size_t ws_size,
                              hipStream_t stream) {
    const int* src = (const int*)d_in[0];
    const int* dst = (const int*)d_in[1];
    const void* nfeats = d_in[2];
    // d_in[3] = efeats, unused
    const void* W1  = d_in[4];
    const void* al1 = d_in[5];
    const void* ar1 = d_in[6];
    const void* b1  = d_in[7];
    const void* W2  = d_in[8];
    const void* al2 = d_in[9];
    const void* ar2 = d_in[10];
    const void* b2  = d_in[11];
    const void* Wp  = d_in[12];
    const void* bp  = d_in[13];

    const int E = in_sizes[0];
    const int N = in_sizes[2] / KIN;

    // workspace layout (256B aligned), all intermediates fp32 (~86 MB)
    size_t o = 0;
    auto alloc = [&](size_t bytes) { size_t r = o; o = (o + bytes + 255) & ~(size_t)255; return r; };
    char* ws = (char*)d_ws;
    int*   flag = (int*)  (ws + alloc(4));
    int*   deg  = (int*)  (ws + alloc((size_t)N * 4));
    int*   off  = (int*)  (ws + alloc((size_t)(N + 1) * 4));
    int*   cur  = (int*)  (ws + alloc((size_t)N * 4));
    int*   csr  = (int*)  (ws + alloc((size_t)E * 4));
    float* f    = (float*)(ws + alloc((size_t)N * HD * 4));
    float* h    = (float*)(ws + alloc((size_t)N * HD * 4));
    float* el4  = (float*)(ws + alloc((size_t)N * 16));
    float* er4  = (float*)(ws + alloc((size_t)N * 16));
    float* P    = (float*)(ws + alloc((size_t)N * NC * 4));
    float* Q    = (float*)(ws + alloc((size_t)N * NC * 4));
    (void)ws_size; (void)n_in; (void)out_size;

    const int TB = 256;
    int gE   = (E + TB - 1) / TB;
    int gN   = (N + TB - 1) / TB;
    int gMC  = (N * HD + TB - 1) / TB;
    int gAgg = (N + 3) / 4;        // 4 waves (nodes) per 256-thread block
    int gPQ  = (N * NC + TB - 1) / TB;
    int gSc  = (E * NC + TB - 1) / TB;

    k_probe<<<1, 64, 0, stream>>>(W1, flag);

    // CSR build (dst-indexed)
    k_zero<<<gN, TB, 0, stream>>>(deg, N);
    k_hist<<<gE, TB, 0, stream>>>(dst, E, deg);
    k_scan<<<1, 1024, 0, stream>>>(deg, N, off, cur);
    k_fill<<<gE, TB, 0, stream>>>(src, dst, E, cur, csr);

    // layer 1
    k_gemm<<<gMC, TB, 0, stream>>>(nfeats, W1, f, N, KIN, HD, flag, 1);
    k_elr<<<N, HD, 0, stream>>>(f, al1, ar1, el4, er4, N, flag);
    k_agg<<<gAgg, TB, 0, stream>>>(f, (const float4*)el4, er4, off, csr, b1, h, N, flag);

    // layer 2
    k_gemm<<<gMC, TB, 0, stream>>>(h, W2, f, N, HD, HD, flag, 0);
    k_elr<<<N, HD, 0, stream>>>(f, al2, ar2, el4, er4, N, flag);
    k_agg<<<gAgg, TB, 0, stream>>>(f, (const float4*)el4, er4, off, csr, b2, h, N, flag);

    // predictor: P = h @ Wp[:HD], Q = h @ Wp[HD:], score = P[src]+Q[dst]+bp
    k_gemm<<<gPQ, TB, 0, stream>>>(h, Wp, P, N, HD, NC, flag, 2);
    k_gemm<<<gPQ, TB, 0, stream>>>(h, Wp, Q, N, HD, NC, flag, 3);
    k_score<<<gSc, TB, 0, stream>>>(src, dst, P, Q, bp, d_out, E, flag);
}

// Round 3
// 753.472 us; speedup vs baseline: 2.8305x; 2.8305x over previous
//
#include <hip/hip_runtime.h>
#include <cstdint>

// GAT: N=50000 nodes, E=800000 edges, 128 -> 3 heads x 64, 2 layers, 10 classes
constexpr int KIN = 128;   // NDIM_IN
constexpr int HD  = 192;   // H * NDIM_OUT
constexpr int NC  = 10;    // CLASS_NUM
#define NEG_SLOPE 0.2f

typedef __attribute__((ext_vector_type(8))) short bf16x8;
typedef __attribute__((ext_vector_type(4))) float f32x4;

__device__ __forceinline__ float b2f(unsigned short u) {
    union { unsigned int i; float f; } x; x.i = ((unsigned int)u) << 16; return x.f;
}
__device__ __forceinline__ unsigned short f2b(float f) {
    union { float f; unsigned int i; } x; x.f = f;
    unsigned int r = x.i + 0x7FFFu + ((x.i >> 16) & 1u);   // RNE
    return (unsigned short)(r >> 16);
}
// dtype-polymorphic load/store: isbf=1 -> bf16 bits, else fp32
__device__ __forceinline__ float gload(const void* p, long i, int isbf) {
    return isbf ? b2f(((const unsigned short*)p)[i]) : ((const float*)p)[i];
}
__device__ __forceinline__ void gstore(void* p, long i, float v, int isbf) {
    if (isbf) ((unsigned short*)p)[i] = f2b(v);
    else      ((float*)p)[i] = v;
}
__device__ __forceinline__ float lrelu(float v) { return v > 0.f ? v : NEG_SLOPE * v; }

// ---- dtype probe: bf16 interp of fp32 data blows up on random low halves ----
__global__ void k_probe(const void* W, int* flag) {
    if (threadIdx.x != 0 || blockIdx.x != 0) return;
    const unsigned short* u = (const unsigned short*)W;
    float mx = 0.f;
    for (int i = 0; i < 64; ++i) {
        float v = fabsf(b2f(u[i]));
        if (!(v < 1e30f)) v = 1e30f;
        mx = fmaxf(mx, v);
    }
    *flag = (mx < 1e4f) ? 1 : 0;       // 1 = bf16, 0 = fp32
}

__global__ void k_zero(int* p, int n) {
    int i = blockIdx.x * blockDim.x + threadIdx.x;
    if (i < n) p[i] = 0;
}

// ---- convert any-dtype input to bf16 staging buffer (identity if already bf16) ----
__global__ void k_cvt(const void* __restrict__ X, unsigned short* __restrict__ Y, long n,
                      const int* __restrict__ flag) {
    long i = (long)blockIdx.x * blockDim.x + threadIdx.x;
    if (i < n) Y[i] = f2b(gload(X, i, *flag));
}

// ---- pack W[K x Creal] (+rowOff) into B-fragment order for 16x16x32 bf16 MFMA ----
// Bp[((ct*KS+ks)*64+lane)*8+j] = W[rowOff + ks*32+(lane>>4)*8+j][ct*16+(lane&15)], zero-padded
__global__ void k_pack(const void* __restrict__ W, unsigned short* __restrict__ Bp,
                       int K, int Creal, int CT, int KS, long rowOff,
                       const int* __restrict__ flag) {
    int t = blockIdx.x * blockDim.x + threadIdx.x;
    int total = CT * KS * 512;
    if (t >= total) return;
    int isb = *flag;
    int j = t & 7, lane = (t >> 3) & 63;
    int ks = (t >> 9) % KS, ct = t / (KS * 512);
    int k = ks * 32 + ((lane >> 4) << 3) + j;
    int c = ct * 16 + (lane & 15);
    float v = 0.f;
    if (k < K && c < Creal) v = gload(W, (rowOff + k) * (long)Creal + c, isb);
    Bp[t] = f2b(v);
}

// ---- MFMA GEMM: out[M x Cout] = A[M x K](bf16) @ Bpacked; one wave = 16 rows x CT col-tiles ----
template<int CT, int KS>
__global__ void k_mm(const unsigned short* __restrict__ A, const unsigned short* __restrict__ Bp,
                     float* __restrict__ out, int M, int K, int Cout) {
    int wid = threadIdx.x >> 6, lane = threadIdx.x & 63;
    int rt = blockIdx.x * 4 + wid;
    if (rt * 16 >= M) return;
    int mrow = rt * 16 + (lane & 15);
    int kq = (lane >> 4) << 3;                 // quad's k offset within 32-chunk
    f32x4 acc[CT];
#pragma unroll
    for (int ct = 0; ct < CT; ++ct) acc[ct] = (f32x4){0.f, 0.f, 0.f, 0.f};
    const unsigned short* arow = A + (long)mrow * K + kq;
    const bf16x8* bp = (const bf16x8*)Bp;
#pragma unroll
    for (int ks = 0; ks < KS; ++ks) {
        bf16x8 a = *(const bf16x8*)(arow + ks * 32);
#pragma unroll
        for (int ct = 0; ct < CT; ++ct) {
            bf16x8 b = bp[(ct * KS + ks) * 64 + lane];
            acc[ct] = __builtin_amdgcn_mfma_f32_16x16x32_bf16(a, b, acc[ct], 0, 0, 0);
        }
    }
    int r0 = rt * 16 + ((lane >> 4) << 2);
    int c0 = lane & 15;
#pragma unroll
    for (int ct = 0; ct < CT; ++ct) {
        int c = ct * 16 + c0;
        if (c < Cout) {
#pragma unroll
            for (int r = 0; r < 4; ++r)
                out[(long)(r0 + r) * Cout + c] = acc[ct][r];
        }
    }
}

// ---------------- CSR build ----------------
__global__ void k_hist(const int* __restrict__ dst, int E, int* __restrict__ deg) {
    int i = blockIdx.x * blockDim.x + threadIdx.x;
    if (i < E) atomicAdd(&deg[dst[i]], 1);
}

__global__ void k_scan(const int* __restrict__ deg, int n, int* __restrict__ off, int* __restrict__ cur) {
    __shared__ int sh[1024];
    __shared__ int carrysh;
    int tid = threadIdx.x;
    if (tid == 0) carrysh = 0;
    __syncthreads();
    for (int base = 0; base < n; base += 1024) {
        int i = base + tid;
        int v = (i < n) ? deg[i] : 0;
        sh[tid] = v;
        __syncthreads();
        for (int s = 1; s < 1024; s <<= 1) {
            int t = (tid >= s) ? sh[tid - s] : 0;
            __syncthreads();
            sh[tid] += t;
            __syncthreads();
        }
        if (i < n) {
            int excl = carrysh + sh[tid] - v;
            off[i] = excl;
            cur[i] = excl;
        }
        __syncthreads();
        if (tid == 0) carrysh += sh[1023];
        __syncthreads();
    }
    if (tid == 0) off[n] = carrysh;
}

__global__ void k_fill(const int* __restrict__ src, const int* __restrict__ dst, int E,
                       int* __restrict__ cur, int* __restrict__ csr) {
    int i = blockIdx.x * blockDim.x + threadIdx.x;
    if (i < E) {
        int p = atomicAdd(&cur[dst[i]], 1);
        csr[p] = src[i];
    }
}

// ---------- el/er per node; f internal fp32; al/ar harness inputs ----------
__global__ void k_elr(const float* __restrict__ f, const void* __restrict__ al,
                      const void* __restrict__ ar, float* __restrict__ el4,
                      float* __restrict__ er4, int Nn, const int* __restrict__ flag) {
    int n = blockIdx.x;
    if (n >= Nn) return;
    int isb = *flag;
    int j = threadIdx.x;      // 0..191
    float fv = f[(long)n * HD + j];
    float e_l = fv * gload(al, j, isb);
    float e_r = fv * gload(ar, j, isb);
    for (int d = 1; d < 64; d <<= 1) {
        e_l += __shfl_xor(e_l, d);
        e_r += __shfl_xor(e_r, d);
    }
    if ((j & 63) == 0) {
        int h = j >> 6;
        el4[n * 4 + h] = e_l;
        er4[n * 4 + h] = e_r;
    }
}

// ---------- softmax + aggregation, one wave per node; out fp32 h AND bf16 hb ----------
__global__ void k_agg(const float* __restrict__ f, const float4* __restrict__ el4,
                      const float* __restrict__ er4, const int* __restrict__ off,
                      const int* __restrict__ csr, const void* __restrict__ bias,
                      float* __restrict__ out, unsigned short* __restrict__ outb,
                      int Nn, const int* __restrict__ flag) {
    int lane = threadIdx.x & 63;
    int n = blockIdx.x * (blockDim.x >> 6) + (threadIdx.x >> 6);
    if (n >= Nn) return;
    int isb = *flag;
    int s0 = off[n], s1 = off[n + 1];
    float er0 = er4[n * 4 + 0], er1 = er4[n * 4 + 1], er2 = er4[n * 4 + 2];

    float m0 = -1e30f, m1 = -1e30f, m2 = -1e30f;
    for (int e = s0 + lane; e < s1; e += 64) {
        float4 el = el4[csr[e]];
        m0 = fmaxf(m0, lrelu(el.x + er0));
        m1 = fmaxf(m1, lrelu(el.y + er1));
        m2 = fmaxf(m2, lrelu(el.z + er2));
    }
    for (int d = 1; d < 64; d <<= 1) {
        m0 = fmaxf(m0, __shfl_xor(m0, d));
        m1 = fmaxf(m1, __shfl_xor(m1, d));
        m2 = fmaxf(m2, __shfl_xor(m2, d));
    }
    float d0 = 0.f, d1 = 0.f, d2 = 0.f;
    for (int e = s0 + lane; e < s1; e += 64) {
        float4 el = el4[csr[e]];
        d0 += __expf(lrelu(el.x + er0) - m0);
        d1 += __expf(lrelu(el.y + er1) - m1);
        d2 += __expf(lrelu(el.z + er2) - m2);
    }
    for (int d = 1; d < 64; d <<= 1) {
        d0 += __shfl_xor(d0, d);
        d1 += __shfl_xor(d1, d);
        d2 += __shfl_xor(d2, d);
    }
    float id0 = 1.f / d0, id1 = 1.f / d1, id2 = 1.f / d2;

    float a0 = 0.f, a1 = 0.f, a2 = 0.f;
    for (int e = s0; e < s1; ++e) {
        int s = csr[e];
        float4 el = el4[s];
        float w0 = __expf(lrelu(el.x + er0) - m0) * id0;
        float w1 = __expf(lrelu(el.y + er1) - m1) * id1;
        float w2 = __expf(lrelu(el.z + er2) - m2) * id2;
        const float* fr = f + (long)s * HD;
        a0 += w0 * fr[lane];
        a1 += w1 * fr[lane + 64];
        a2 += w2 * fr[lane + 128];
    }
    a0 = fmaxf(a0 + gload(bias, lane,       isb), 0.f);
    a1 = fmaxf(a1 + gload(bias, lane + 64,  isb), 0.f);
    a2 = fmaxf(a2 + gload(bias, lane + 128, isb), 0.f);
    float* orow = out + (long)n * HD;
    orow[lane]       = a0;
    orow[lane + 64]  = a1;
    orow[lane + 128] = a2;
    unsigned short* brow = outb + (long)n * HD;
    brow[lane]       = f2b(a0);
    brow[lane + 64]  = f2b(a1);
    brow[lane + 128] = f2b(a2);
}

// ---------- per-edge score: out[e,c] = P[src,c] + Q[dst,c] + bp[c] ----------
__global__ void k_score(const int* __restrict__ src, const int* __restrict__ dst,
                        const float* __restrict__ P, const float* __restrict__ Q,
                        const void* __restrict__ bp, void* __restrict__ out,
                        int E, const int* __restrict__ flag) {
    int e = blockIdx.x * blockDim.x + threadIdx.x;
    if (e >= E) return;
    int isb = *flag;
    int s = src[e], d = dst[e];
#pragma unroll
    for (int c = 0; c < NC; ++c) {
        float v = P[s * NC + c] + Q[d * NC + c] + gload(bp, c, isb);
        gstore(out, (long)e * NC + c, v, isb);
    }
}

extern "C" void kernel_launch(void* const* d_in, const int* in_sizes, int n_in,
                              void* d_out, int out_size, void* d_ws, size_t ws_size,
                              hipStream_t stream) {
    const int* src = (const int*)d_in[0];
    const int* dst = (const int*)d_in[1];
    const void* nfeats = d_in[2];
    // d_in[3] = efeats, unused
    const void* W1  = d_in[4];
    const void* al1 = d_in[5];
    const void* ar1 = d_in[6];
    const void* b1  = d_in[7];
    const void* W2  = d_in[8];
    const void* al2 = d_in[9];
    const void* ar2 = d_in[10];
    const void* b2  = d_in[11];
    const void* Wp  = d_in[12];
    const void* bp  = d_in[13];

    const int E = in_sizes[0];
    const int N = in_sizes[2] / KIN;

    // workspace layout (256B aligned), ~120 MB
    size_t o = 0;
    auto alloc = [&](size_t bytes) { size_t r = o; o = (o + bytes + 255) & ~(size_t)255; return r; };
    char* ws = (char*)d_ws;
    int*   flag = (int*)  (ws + alloc(4));
    int*   deg  = (int*)  (ws + alloc((size_t)N * 4));
    int*   off  = (int*)  (ws + alloc((size_t)(N + 1) * 4));
    int*   cur  = (int*)  (ws + alloc((size_t)N * 4));
    int*   csr  = (int*)  (ws + alloc((size_t)E * 4));
    float* f    = (float*)(ws + alloc((size_t)N * HD * 4));
    float* h    = (float*)(ws + alloc((size_t)N * HD * 4));
    unsigned short* xb = (unsigned short*)(ws + alloc((size_t)N * KIN * 2));
    unsigned short* hb = (unsigned short*)(ws + alloc((size_t)N * HD * 2));
    unsigned short* Bp1 = (unsigned short*)(ws + alloc((size_t)12 * 4 * 512 * 2));
    unsigned short* Bp2 = (unsigned short*)(ws + alloc((size_t)12 * 6 * 512 * 2));
    unsigned short* BpP = (unsigned short*)(ws + alloc((size_t)1 * 6 * 512 * 2));
    unsigned short* BpQ = (unsigned short*)(ws + alloc((size_t)1 * 6 * 512 * 2));
    float* el4  = (float*)(ws + alloc((size_t)N * 16));
    float* er4  = (float*)(ws + alloc((size_t)N * 16));
    float* P    = (float*)(ws + alloc((size_t)N * NC * 4));
    float* Q    = (float*)(ws + alloc((size_t)N * NC * 4));
    (void)ws_size; (void)n_in; (void)out_size;

    const int TB = 256;
    int gE   = (E + TB - 1) / TB;
    int gN   = (N + TB - 1) / TB;
    int gAgg = (N + 3) / 4;                    // 4 waves (nodes) per block
    int rowTiles = (N + 15) / 16;              // 3125
    int gMM  = (rowTiles + 3) / 4;             // 4 row-tiles per block

    k_probe<<<1, 64, 0, stream>>>(W1, flag);

    // staging: bf16 A inputs + fragment-packed B matrices
    long nx = (long)N * KIN;
    k_cvt<<<(int)((nx + TB - 1) / TB), TB, 0, stream>>>(nfeats, xb, nx, flag);
    k_pack<<<(12 * 4 * 512 + TB - 1) / TB, TB, 0, stream>>>(W1, Bp1, KIN, HD, 12, 4, 0, flag);
    k_pack<<<(12 * 6 * 512 + TB - 1) / TB, TB, 0, stream>>>(W2, Bp2, HD, HD, 12, 6, 0, flag);
    k_pack<<<(6 * 512 + TB - 1) / TB, TB, 0, stream>>>(Wp, BpP, HD, NC, 1, 6, 0, flag);
    k_pack<<<(6 * 512 + TB - 1) / TB, TB, 0, stream>>>(Wp, BpQ, HD, NC, 1, 6, HD, flag);

    // CSR build (dst-indexed)
    k_zero<<<gN, TB, 0, stream>>>(deg, N);
    k_hist<<<gE, TB, 0, stream>>>(dst, E, deg);
    k_scan<<<1, 1024, 0, stream>>>(deg, N, off, cur);
    k_fill<<<gE, TB, 0, stream>>>(src, dst, E, cur, csr);

    // layer 1
    k_mm<12, 4><<<gMM, TB, 0, stream>>>(xb, Bp1, f, N, KIN, HD);
    k_elr<<<N, HD, 0, stream>>>(f, al1, ar1, el4, er4, N, flag);
    k_agg<<<gAgg, TB, 0, stream>>>(f, (const float4*)el4, er4, off, csr, b1, h, hb, N, flag);

    // layer 2
    k_mm<12, 6><<<gMM, TB, 0, stream>>>(hb, Bp2, f, N, HD, HD);
    k_elr<<<N, HD, 0, stream>>>(f, al2, ar2, el4, er4, N, flag);
    k_agg<<<gAgg, TB, 0, stream>>>(f, (const float4*)el4, er4, off, csr, b2, h, hb, N, flag);

    // predictor: P = h @ Wp_top, Q = h @ Wp_bot, score = P[src]+Q[dst]+bp
    k_mm<1, 6><<<gMM, TB, 0, stream>>>(hb, BpP, P, N, HD, NC);
    k_mm<1, 6><<<gMM, TB, 0, stream>>>(hb, BpQ, Q, N, HD, NC);
    k_score<<<gE, TB, 0, stream>>>(src, dst, P, Q, bp, d_out, E, flag);
}

// Round 4
// 525.785 us; speedup vs baseline: 4.0562x; 1.4330x over previous
//
#include <hip/hip_runtime.h>
#include <cstdint>

// GAT: N=50000 nodes, E=800000 edges, 128 -> 3 heads x 64, 2 layers, 10 classes
constexpr int KIN = 128;   // NDIM_IN
constexpr int HD  = 192;   // H * NDIM_OUT
constexpr int NC  = 10;    // CLASS_NUM
#define NEG_SLOPE 0.2f

typedef __attribute__((ext_vector_type(8))) short bf16x8;
typedef __attribute__((ext_vector_type(4))) float f32x4;

__device__ __forceinline__ float b2f(unsigned short u) {
    union { unsigned int i; float f; } x; x.i = ((unsigned int)u) << 16; return x.f;
}
__device__ __forceinline__ unsigned short f2b(float f) {
    union { float f; unsigned int i; } x; x.f = f;
    unsigned int r = x.i + 0x7FFFu + ((x.i >> 16) & 1u);   // RNE
    return (unsigned short)(r >> 16);
}
__device__ __forceinline__ float gload(const void* p, long i, int isbf) {
    return isbf ? b2f(((const unsigned short*)p)[i]) : ((const float*)p)[i];
}
__device__ __forceinline__ void gstore(void* p, long i, float v, int isbf) {
    if (isbf) ((unsigned short*)p)[i] = f2b(v);
    else      ((float*)p)[i] = v;
}
__device__ __forceinline__ float lrelu(float v) { return v > 0.f ? v : NEG_SLOPE * v; }

// ---- dtype probe: bf16 interp of fp32 data blows up on random low halves ----
__global__ void k_probe(const void* W, int* flag) {
    if (threadIdx.x != 0 || blockIdx.x != 0) return;
    const unsigned short* u = (const unsigned short*)W;
    float mx = 0.f;
    for (int i = 0; i < 64; ++i) {
        float v = fabsf(b2f(u[i]));
        if (!(v < 1e30f)) v = 1e30f;
        mx = fmaxf(mx, v);
    }
    *flag = (mx < 1e4f) ? 1 : 0;       // 1 = bf16, 0 = fp32
}

__global__ void k_zero(int* p, int n) {
    int i = blockIdx.x * blockDim.x + threadIdx.x;
    if (i < n) p[i] = 0;
}

// ---- convert any-dtype input to bf16 staging (identity if already bf16) ----
__global__ void k_cvt(const void* __restrict__ X, unsigned short* __restrict__ Y, long n,
                      const int* __restrict__ flag) {
    long i = (long)blockIdx.x * blockDim.x + threadIdx.x;
    if (i < n) Y[i] = f2b(gload(X, i, *flag));
}

// ---- pack W[K x Creal] (+rowOff) into B-fragment order for 16x16x32 bf16 MFMA ----
__global__ void k_pack(const void* __restrict__ W, unsigned short* __restrict__ Bp,
                       int K, int Creal, int CT, int KS, long rowOff,
                       const int* __restrict__ flag) {
    int t = blockIdx.x * blockDim.x + threadIdx.x;
    int total = CT * KS * 512;
    if (t >= total) return;
    int isb = *flag;
    int j = t & 7, lane = (t >> 3) & 63;
    int ks = (t >> 9) % KS, ct = t / (KS * 512);
    int k = ks * 32 + ((lane >> 4) << 3) + j;
    int c = ct * 16 + (lane & 15);
    float v = 0.f;
    if (k < K && c < Creal) v = gload(W, (rowOff + k) * (long)Creal + c, isb);
    Bp[t] = f2b(v);
}

// ---- MFMA GEMM + fused el/er epilogue. One wave = 16 rows x CT col-tiles.
// Writes bf16 features fb[M x Cout]; if ELR, also el4/er4 [M x 4] per head.
template<int CT, int KS, int ELR>
__global__ void k_mm(const unsigned short* __restrict__ A, const unsigned short* __restrict__ Bp,
                     unsigned short* __restrict__ fb, const void* __restrict__ al,
                     const void* __restrict__ ar, float* __restrict__ el4,
                     float* __restrict__ er4, int M, int Cout, const int* __restrict__ flag) {
    int wid = threadIdx.x >> 6, lane = threadIdx.x & 63;
    int rt = blockIdx.x * 4 + wid;
    if (rt * 16 >= M) return;
    const int K = KS * 32;
    int mrow = rt * 16 + (lane & 15);
    int kq = (lane >> 4) << 3;
    f32x4 acc[CT];
#pragma unroll
    for (int ct = 0; ct < CT; ++ct) acc[ct] = (f32x4){0.f, 0.f, 0.f, 0.f};
    const unsigned short* arow = A + (long)mrow * K + kq;
    const bf16x8* bp = (const bf16x8*)Bp;
#pragma unroll
    for (int ks = 0; ks < KS; ++ks) {
        bf16x8 a = *(const bf16x8*)(arow + ks * 32);
#pragma unroll
        for (int ct = 0; ct < CT; ++ct) {
            bf16x8 b = bp[(ct * KS + ks) * 64 + lane];
            acc[ct] = __builtin_amdgcn_mfma_f32_16x16x32_bf16(a, b, acc[ct], 0, 0, 0);
        }
    }
    int quad = lane >> 4, c0 = lane & 15;
    int rbase = rt * 16 + quad * 4;
    // bf16 feature store
#pragma unroll
    for (int ct = 0; ct < CT; ++ct)
#pragma unroll
        for (int r = 0; r < 4; ++r)
            fb[(long)(rbase + r) * Cout + ct * 16 + c0] = f2b(acc[ct][r]);
    if (ELR) {
        int isb = *flag;
        float pl[3][4], pr[3][4];
#pragma unroll
        for (int h = 0; h < 3; ++h)
#pragma unroll
            for (int r = 0; r < 4; ++r) { pl[h][r] = 0.f; pr[h][r] = 0.f; }
#pragma unroll
        for (int ct = 0; ct < CT; ++ct) {
            int h = ct >> 2;                       // head = col/64
            float wl = gload(al, ct * 16 + c0, isb);
            float wr = gload(ar, ct * 16 + c0, isb);
#pragma unroll
            for (int r = 0; r < 4; ++r) {
                pl[h][r] += acc[ct][r] * wl;
                pr[h][r] += acc[ct][r] * wr;
            }
        }
#pragma unroll
        for (int d = 1; d < 16; d <<= 1)
#pragma unroll
            for (int h = 0; h < 3; ++h)
#pragma unroll
                for (int r = 0; r < 4; ++r) {
                    pl[h][r] += __shfl_xor(pl[h][r], d);
                    pr[h][r] += __shfl_xor(pr[h][r], d);
                }
        if (c0 == 0) {
#pragma unroll
            for (int r = 0; r < 4; ++r)
#pragma unroll
                for (int h = 0; h < 3; ++h) {
                    el4[(long)(rbase + r) * 4 + h] = pl[h][r];
                    er4[(long)(rbase + r) * 4 + h] = pr[h][r];
                }
        }
    }
}

// ---- fused P/Q gemm: PQ[M x 20], PQ[n][0:10]=h@Wp_top, PQ[n][10:20]=h@Wp_bot ----
__global__ void k_mmpq(const unsigned short* __restrict__ A, const unsigned short* __restrict__ Bp,
                       float* __restrict__ PQ, int M) {
    constexpr int CT = 2, KS = 6;
    int wid = threadIdx.x >> 6, lane = threadIdx.x & 63;
    int rt = blockIdx.x * 4 + wid;
    if (rt * 16 >= M) return;
    const int K = KS * 32;
    int mrow = rt * 16 + (lane & 15);
    int kq = (lane >> 4) << 3;
    f32x4 acc[CT];
#pragma unroll
    for (int ct = 0; ct < CT; ++ct) acc[ct] = (f32x4){0.f, 0.f, 0.f, 0.f};
    const unsigned short* arow = A + (long)mrow * K + kq;
    const bf16x8* bp = (const bf16x8*)Bp;
#pragma unroll
    for (int ks = 0; ks < KS; ++ks) {
        bf16x8 a = *(const bf16x8*)(arow + ks * 32);
#pragma unroll
        for (int ct = 0; ct < CT; ++ct) {
            bf16x8 b = bp[(ct * KS + ks) * 64 + lane];
            acc[ct] = __builtin_amdgcn_mfma_f32_16x16x32_bf16(a, b, acc[ct], 0, 0, 0);
        }
    }
    int quad = lane >> 4, c0 = lane & 15;
    int rbase = rt * 16 + quad * 4;
    if (c0 < NC) {
#pragma unroll
        for (int ct = 0; ct < CT; ++ct)
#pragma unroll
            for (int r = 0; r < 4; ++r)
                PQ[(long)(rbase + r) * (2 * NC) + ct * NC + c0] = acc[ct][r];
    }
}

// ---------------- CSR build ----------------
__global__ void k_hist(const int* __restrict__ dst, int E, int* __restrict__ deg) {
    int i = blockIdx.x * blockDim.x + threadIdx.x;
    if (i < E) atomicAdd(&deg[dst[i]], 1);
}

__global__ void k_scan1(const int* __restrict__ deg, int n, int* __restrict__ off,
                        int* __restrict__ bsum) {
    __shared__ int sh[1024];
    int tid = threadIdx.x, i = blockIdx.x * 1024 + tid;
    int v = (i < n) ? deg[i] : 0;
    sh[tid] = v;
    __syncthreads();
    for (int s = 1; s < 1024; s <<= 1) {
        int t = (tid >= s) ? sh[tid - s] : 0;
        __syncthreads();
        sh[tid] += t;
        __syncthreads();
    }
    if (i < n) off[i] = sh[tid] - v;       // block-local exclusive
    if (tid == 1023) bsum[blockIdx.x] = sh[tid];
}

__global__ void k_scan2(int* __restrict__ bsum, int nb, int* __restrict__ off, int n) {
    int tid = threadIdx.x;                  // 64 threads, nb <= 64
    int v = (tid < nb) ? bsum[tid] : 0;
    int incl = v;
    for (int s = 1; s < 64; s <<= 1) {
        int t = __shfl_up(incl, s);
        if (tid >= s) incl += t;
    }
    if (tid < nb) bsum[tid] = incl - v;     // exclusive block offsets
    if (tid == 63) off[n] = incl;           // grand total
}

__global__ void k_scan3(int* __restrict__ off, const int* __restrict__ bsum, int n,
                        int* __restrict__ cur) {
    int i = blockIdx.x * 1024 + threadIdx.x;
    if (i < n) {
        int v = off[i] + bsum[blockIdx.x];
        off[i] = v;
        cur[i] = v;
    }
}

__global__ void k_fill(const int* __restrict__ src, const int* __restrict__ dst, int E,
                       int* __restrict__ cur, int* __restrict__ csr) {
    int i = blockIdx.x * blockDim.x + threadIdx.x;
    if (i < E) {
        int p = atomicAdd(&cur[dst[i]], 1);
        csr[p] = src[i];
    }
}

// ---- softmax + aggregation, one wave per node; bf16 features in, bf16 out ----
__global__ void k_agg(const unsigned short* __restrict__ fb, const float4* __restrict__ el4,
                      const float* __restrict__ er4, const int* __restrict__ off,
                      const int* __restrict__ csr, const void* __restrict__ bias,
                      unsigned short* __restrict__ outb, int Nn, const int* __restrict__ flag) {
    int lane = threadIdx.x & 63;
    int n = blockIdx.x * (blockDim.x >> 6) + (threadIdx.x >> 6);
    if (n >= Nn) return;
    int isb = *flag;
    int s0 = off[n], s1 = off[n + 1];
    int deg = s1 - s0;
    float er0 = er4[n * 4 + 0], er1 = er4[n * 4 + 1], er2 = er4[n * 4 + 2];
    float a0 = 0.f, a1 = 0.f, a2 = 0.f;

    if (deg > 0 && deg <= 64) {
        // fast path: whole edge list fits one wave batch
        int e = s0 + lane;
        bool on = e < s1;
        int sIdx = on ? csr[e] : 0;
        float4 el = el4[sIdx];
        float t0 = on ? lrelu(el.x + er0) : -1e30f;
        float t1 = on ? lrelu(el.y + er1) : -1e30f;
        float t2 = on ? lrelu(el.z + er2) : -1e30f;
        float m0 = t0, m1 = t1, m2 = t2;
        for (int d = 1; d < 64; d <<= 1) {
            m0 = fmaxf(m0, __shfl_xor(m0, d));
            m1 = fmaxf(m1, __shfl_xor(m1, d));
            m2 = fmaxf(m2, __shfl_xor(m2, d));
        }
        float w0 = on ? __expf(t0 - m0) : 0.f;
        float w1 = on ? __expf(t1 - m1) : 0.f;
        float w2 = on ? __expf(t2 - m2) : 0.f;
        float d0 = w0, d1 = w1, d2 = w2;
        for (int d = 1; d < 64; d <<= 1) {
            d0 += __shfl_xor(d0, d);
            d1 += __shfl_xor(d1, d);
            d2 += __shfl_xor(d2, d);
        }
        w0 *= 1.f / d0; w1 *= 1.f / d1; w2 *= 1.f / d2;
#pragma unroll 4
        for (int j = 0; j < deg; ++j) {
            int s = __shfl(sIdx, j);
            float u0 = __shfl(w0, j), u1 = __shfl(w1, j), u2 = __shfl(w2, j);
            const unsigned short* fr = fb + (long)s * HD;
            a0 += u0 * b2f(fr[lane]);
            a1 += u1 * b2f(fr[lane + 64]);
            a2 += u2 * b2f(fr[lane + 128]);
        }
    } else if (deg > 64) {
        // generic 3-pass path
        float m0 = -1e30f, m1 = -1e30f, m2 = -1e30f;
        for (int e = s0 + lane; e < s1; e += 64) {
            float4 el = el4[csr[e]];
            m0 = fmaxf(m0, lrelu(el.x + er0));
            m1 = fmaxf(m1, lrelu(el.y + er1));
            m2 = fmaxf(m2, lrelu(el.z + er2));
        }
        for (int d = 1; d < 64; d <<= 1) {
            m0 = fmaxf(m0, __shfl_xor(m0, d));
            m1 = fmaxf(m1, __shfl_xor(m1, d));
            m2 = fmaxf(m2, __shfl_xor(m2, d));
        }
        float d0 = 0.f, d1 = 0.f, d2 = 0.f;
        for (int e = s0 + lane; e < s1; e += 64) {
            float4 el = el4[csr[e]];
            d0 += __expf(lrelu(el.x + er0) - m0);
            d1 += __expf(lrelu(el.y + er1) - m1);
            d2 += __expf(lrelu(el.z + er2) - m2);
        }
        for (int d = 1; d < 64; d <<= 1) {
            d0 += __shfl_xor(d0, d);
            d1 += __shfl_xor(d1, d);
            d2 += __shfl_xor(d2, d);
        }
        float id0 = 1.f / d0, id1 = 1.f / d1, id2 = 1.f / d2;
        for (int e = s0; e < s1; ++e) {
            int s = csr[e];
            float4 el = el4[s];
            float w0 = __expf(lrelu(el.x + er0) - m0) * id0;
            float w1 = __expf(lrelu(el.y + er1) - m1) * id1;
            float w2 = __expf(lrelu(el.z + er2) - m2) * id2;
            const unsigned short* fr = fb + (long)s * HD;
            a0 += w0 * b2f(fr[lane]);
            a1 += w1 * b2f(fr[lane + 64]);
            a2 += w2 * b2f(fr[lane + 128]);
        }
    }
    a0 = fmaxf(a0 + gload(bias, lane,       isb), 0.f);
    a1 = fmaxf(a1 + gload(bias, lane + 64,  isb), 0.f);
    a2 = fmaxf(a2 + gload(bias, lane + 128, isb), 0.f);
    unsigned short* brow = outb + (long)n * HD;
    brow[lane]       = f2b(a0);
    brow[lane + 64]  = f2b(a1);
    brow[lane + 128] = f2b(a2);
}

// ---- per-edge score: out[e,c] = PQ[src][c] + PQ[dst][10+c] + bp[c] ----
__global__ void k_score(const int* __restrict__ src, const int* __restrict__ dst,
                        const float* __restrict__ PQ, const void* __restrict__ bp,
                        void* __restrict__ out, int E, const int* __restrict__ flag) {
    int e = blockIdx.x * blockDim.x + threadIdx.x;
    if (e >= E) return;
    int isb = *flag;
    long s = (long)src[e] * (2 * NC), d = (long)dst[e] * (2 * NC);
#pragma unroll
    for (int c = 0; c < NC; ++c) {
        float v = PQ[s + c] + PQ[d + NC + c] + gload(bp, c, isb);
        gstore(out, (long)e * NC + c, v, isb);
    }
}

extern "C" void kernel_launch(void* const* d_in, const int* in_sizes, int n_in,
                              void* d_out, int out_size, void* d_ws, size_t ws_size,
                              hipStream_t stream) {
    const int* src = (const int*)d_in[0];
    const int* dst = (const int*)d_in[1];
    const void* nfeats = d_in[2];
    // d_in[3] = efeats, unused
    const void* W1  = d_in[4];
    const void* al1 = d_in[5];
    const void* ar1 = d_in[6];
    const void* b1  = d_in[7];
    const void* W2  = d_in[8];
    const void* al2 = d_in[9];
    const void* ar2 = d_in[10];
    const void* b2  = d_in[11];
    const void* Wp  = d_in[12];
    const void* bp  = d_in[13];

    const int E = in_sizes[0];
    const int N = in_sizes[2] / KIN;

    // workspace layout (256B aligned), ~60 MB
    size_t o = 0;
    auto alloc = [&](size_t bytes) { size_t r = o; o = (o + bytes + 255) & ~(size_t)255; return r; };
    char* ws = (char*)d_ws;
    int*   flag = (int*)  (ws + alloc(4));
    int*   deg  = (int*)  (ws + alloc((size_t)N * 4));
    int*   off  = (int*)  (ws + alloc((size_t)(N + 1) * 4));
    int*   cur  = (int*)  (ws + alloc((size_t)N * 4));
    int*   bsum = (int*)  (ws + alloc(64 * 4));
    int*   csr  = (int*)  (ws + alloc((size_t)E * 4));
    unsigned short* xb  = (unsigned short*)(ws + alloc((size_t)N * KIN * 2));
    unsigned short* fb  = (unsigned short*)(ws + alloc((size_t)N * HD * 2));
    unsigned short* hb  = (unsigned short*)(ws + alloc((size_t)N * HD * 2));
    unsigned short* Bp1 = (unsigned short*)(ws + alloc((size_t)12 * 4 * 512 * 2));
    unsigned short* Bp2 = (unsigned short*)(ws + alloc((size_t)12 * 6 * 512 * 2));
    unsigned short* BpPQ= (unsigned short*)(ws + alloc((size_t)2 * 6 * 512 * 2));
    float* el4  = (float*)(ws + alloc((size_t)N * 16));
    float* er4  = (float*)(ws + alloc((size_t)N * 16));
    float* PQ   = (float*)(ws + alloc((size_t)N * 2 * NC * 4));
    (void)ws_size; (void)n_in; (void)out_size;

    const int TB = 256;
    int gE   = (E + TB - 1) / TB;
    int gN   = (N + TB - 1) / TB;
    int gAgg = (N + 3) / 4;                    // 4 waves (nodes) per block
    int rowTiles = (N + 15) / 16;              // 3125
    int gMM  = (rowTiles + 3) / 4;
    int nb   = (N + 1023) / 1024;              // scan blocks (<= 64)

    k_probe<<<1, 64, 0, stream>>>(W1, flag);

    // staging: bf16 A input + fragment-packed B matrices
    long nx = (long)N * KIN;
    k_cvt<<<(int)((nx + TB - 1) / TB), TB, 0, stream>>>(nfeats, xb, nx, flag);
    k_pack<<<(12 * 4 * 512 + TB - 1) / TB, TB, 0, stream>>>(W1, Bp1, KIN, HD, 12, 4, 0, flag);
    k_pack<<<(12 * 6 * 512 + TB - 1) / TB, TB, 0, stream>>>(W2, Bp2, HD, HD, 12, 6, 0, flag);
    k_pack<<<(6 * 512 + TB - 1) / TB, TB, 0, stream>>>(Wp, BpPQ,            HD, NC, 1, 6, 0,  flag);
    k_pack<<<(6 * 512 + TB - 1) / TB, TB, 0, stream>>>(Wp, BpPQ + 6 * 512,  HD, NC, 1, 6, HD, flag);

    // CSR build (dst-indexed), hierarchical scan
    k_zero<<<gN, TB, 0, stream>>>(deg, N);
    k_hist<<<gE, TB, 0, stream>>>(dst, E, deg);
    k_scan1<<<nb, 1024, 0, stream>>>(deg, N, off, bsum);
    k_scan2<<<1, 64, 0, stream>>>(bsum, nb, off, N);
    k_scan3<<<nb, 1024, 0, stream>>>(off, bsum, N, cur);
    k_fill<<<gE, TB, 0, stream>>>(src, dst, E, cur, csr);

    // layer 1: fused gemm+el/er, then softmax-aggregate
    k_mm<12, 4, 1><<<gMM, TB, 0, stream>>>(xb, Bp1, fb, al1, ar1, el4, er4, N, HD, flag);
    k_agg<<<gAgg, TB, 0, stream>>>(fb, (const float4*)el4, er4, off, csr, b1, hb, N, flag);

    // layer 2
    k_mm<12, 6, 1><<<gMM, TB, 0, stream>>>(hb, Bp2, fb, al2, ar2, el4, er4, N, HD, flag);
    k_agg<<<gAgg, TB, 0, stream>>>(fb, (const float4*)el4, er4, off, csr, b2, hb, N, flag);

    // predictor
    k_mmpq<<<gMM, TB, 0, stream>>>(hb, BpPQ, PQ, N);
    k_score<<<gE, TB, 0, stream>>>(src, dst, PQ, bp, d_out, E, flag);
}

// Round 5
// 484.237 us; speedup vs baseline: 4.4043x; 1.0858x over previous
//
#include <hip/hip_runtime.h>
#include <cstdint>

// GAT: N=50000 nodes, E=800000 edges, 128 -> 3 heads x 64, 2 layers, 10 classes
constexpr int KIN = 128;   // NDIM_IN
constexpr int HD  = 192;   // H * NDIM_OUT
constexpr int NC  = 10;    // CLASS_NUM
#define NEG_SLOPE 0.2f

typedef __attribute__((ext_vector_type(8))) short bf16x8;
typedef __attribute__((ext_vector_type(4))) float f32x4;

__device__ __forceinline__ float b2f(unsigned short u) {
    union { unsigned int i; float f; } x; x.i = ((unsigned int)u) << 16; return x.f;
}
__device__ __forceinline__ unsigned short f2b(float f) {
    union { float f; unsigned int i; } x; x.f = f;
    unsigned int r = x.i + 0x7FFFu + ((x.i >> 16) & 1u);   // RNE
    return (unsigned short)(r >> 16);
}
__device__ __forceinline__ float gload(const void* p, long i, int isbf) {
    return isbf ? b2f(((const unsigned short*)p)[i]) : ((const float*)p)[i];
}
__device__ __forceinline__ float lrelu(float v) { return v > 0.f ? v : NEG_SLOPE * v; }

// ---- dtype probe: bf16 interp of fp32 data blows up on random low halves ----
__global__ void k_probe(const void* W, int* flag) {
    if (threadIdx.x != 0 || blockIdx.x != 0) return;
    const unsigned short* u = (const unsigned short*)W;
    float mx = 0.f;
    for (int i = 0; i < 64; ++i) {
        float v = fabsf(b2f(u[i]));
        if (!(v < 1e30f)) v = 1e30f;
        mx = fmaxf(mx, v);
    }
    *flag = (mx < 1e4f) ? 1 : 0;       // 1 = bf16, 0 = fp32
}

__global__ void k_zero(int* p, int n) {
    int i = blockIdx.x * blockDim.x + threadIdx.x;
    if (i < n) p[i] = 0;
}

// ---- convert any-dtype input to bf16 staging (identity if already bf16) ----
__global__ void k_cvt(const void* __restrict__ X, unsigned short* __restrict__ Y, long n,
                      const int* __restrict__ flag) {
    long i = (long)blockIdx.x * blockDim.x + threadIdx.x;
    if (i < n) Y[i] = f2b(gload(X, i, *flag));
}

// ---- pack W[K x Creal] (+rowOff) into B-fragment order for 16x16x32 bf16 MFMA ----
__global__ void k_pack(const void* __restrict__ W, unsigned short* __restrict__ Bp,
                       int K, int Creal, int CT, int KS, long rowOff,
                       const int* __restrict__ flag) {
    int t = blockIdx.x * blockDim.x + threadIdx.x;
    int total = CT * KS * 512;
    if (t >= total) return;
    int isb = *flag;
    int j = t & 7, lane = (t >> 3) & 63;
    int ks = (t >> 9) % KS, ct = t / (KS * 512);
    int k = ks * 32 + ((lane >> 4) << 3) + j;
    int c = ct * 16 + (lane & 15);
    float v = 0.f;
    if (k < K && c < Creal) v = gload(W, (rowOff + k) * (long)Creal + c, isb);
    Bp[t] = f2b(v);
}

// ---- MFMA GEMM + fused el/er epilogue. One wave = 16 rows x CT col-tiles.
template<int CT, int KS, int ELR>
__global__ void k_mm(const unsigned short* __restrict__ A, const unsigned short* __restrict__ Bp,
                     unsigned short* __restrict__ fb, const void* __restrict__ al,
                     const void* __restrict__ ar, float* __restrict__ el4,
                     float* __restrict__ er4, int M, int Cout, const int* __restrict__ flag) {
    int wid = threadIdx.x >> 6, lane = threadIdx.x & 63;
    int rt = blockIdx.x * 4 + wid;
    if (rt * 16 >= M) return;
    const int K = KS * 32;
    int mrow = rt * 16 + (lane & 15);
    int kq = (lane >> 4) << 3;
    f32x4 acc[CT];
#pragma unroll
    for (int ct = 0; ct < CT; ++ct) acc[ct] = (f32x4){0.f, 0.f, 0.f, 0.f};
    const unsigned short* arow = A + (long)mrow * K + kq;
    const bf16x8* bp = (const bf16x8*)Bp;
#pragma unroll
    for (int ks = 0; ks < KS; ++ks) {
        bf16x8 a = *(const bf16x8*)(arow + ks * 32);
#pragma unroll
        for (int ct = 0; ct < CT; ++ct) {
            bf16x8 b = bp[(ct * KS + ks) * 64 + lane];
            acc[ct] = __builtin_amdgcn_mfma_f32_16x16x32_bf16(a, b, acc[ct], 0, 0, 0);
        }
    }
    int quad = lane >> 4, c0 = lane & 15;
    int rbase = rt * 16 + quad * 4;
#pragma unroll
    for (int ct = 0; ct < CT; ++ct)
#pragma unroll
        for (int r = 0; r < 4; ++r)
            fb[(long)(rbase + r) * Cout + ct * 16 + c0] = f2b(acc[ct][r]);
    if (ELR) {
        int isb = *flag;
        float pl[3][4], pr[3][4];
#pragma unroll
        for (int h = 0; h < 3; ++h)
#pragma unroll
            for (int r = 0; r < 4; ++r) { pl[h][r] = 0.f; pr[h][r] = 0.f; }
#pragma unroll
        for (int ct = 0; ct < CT; ++ct) {
            int h = ct >> 2;                       // head = col/64
            float wl = gload(al, ct * 16 + c0, isb);
            float wr = gload(ar, ct * 16 + c0, isb);
#pragma unroll
            for (int r = 0; r < 4; ++r) {
                pl[h][r] += acc[ct][r] * wl;
                pr[h][r] += acc[ct][r] * wr;
            }
        }
#pragma unroll
        for (int d = 1; d < 16; d <<= 1)
#pragma unroll
            for (int h = 0; h < 3; ++h)
#pragma unroll
                for (int r = 0; r < 4; ++r) {
                    pl[h][r] += __shfl_xor(pl[h][r], d);
                    pr[h][r] += __shfl_xor(pr[h][r], d);
                }
        if (c0 == 0) {
#pragma unroll
            for (int r = 0; r < 4; ++r)
#pragma unroll
                for (int h = 0; h < 3; ++h) {
                    el4[(long)(rbase + r) * 4 + h] = pl[h][r];
                    er4[(long)(rbase + r) * 4 + h] = pr[h][r];
                }
        }
    }
}

// ---- fused P/Q gemm: PQ[M x 20], PQ[n][0:10]=h@Wp_top, PQ[n][10:20]=h@Wp_bot ----
__global__ void k_mmpq(const unsigned short* __restrict__ A, const unsigned short* __restrict__ Bp,
                       float* __restrict__ PQ, int M) {
    constexpr int CT = 2, KS = 6;
    int wid = threadIdx.x >> 6, lane = threadIdx.x & 63;
    int rt = blockIdx.x * 4 + wid;
    if (rt * 16 >= M) return;
    const int K = KS * 32;
    int mrow = rt * 16 + (lane & 15);
    int kq = (lane >> 4) << 3;
    f32x4 acc[CT];
#pragma unroll
    for (int ct = 0; ct < CT; ++ct) acc[ct] = (f32x4){0.f, 0.f, 0.f, 0.f};
    const unsigned short* arow = A + (long)mrow * K + kq;
    const bf16x8* bp = (const bf16x8*)Bp;
#pragma unroll
    for (int ks = 0; ks < KS; ++ks) {
        bf16x8 a = *(const bf16x8*)(arow + ks * 32);
#pragma unroll
        for (int ct = 0; ct < CT; ++ct) {
            bf16x8 b = bp[(ct * KS + ks) * 64 + lane];
            acc[ct] = __builtin_amdgcn_mfma_f32_16x16x32_bf16(a, b, acc[ct], 0, 0, 0);
        }
    }
    int quad = lane >> 4, c0 = lane & 15;
    int rbase = rt * 16 + quad * 4;
    if (c0 < NC) {
#pragma unroll
        for (int ct = 0; ct < CT; ++ct)
#pragma unroll
            for (int r = 0; r < 4; ++r)
                PQ[(long)(rbase + r) * (2 * NC) + ct * NC + c0] = acc[ct][r];
    }
}

// ---------------- CSR build ----------------
__global__ void k_hist(const int* __restrict__ dst, int E, int* __restrict__ deg) {
    int i = blockIdx.x * blockDim.x + threadIdx.x;
    if (i < E) atomicAdd(&deg[dst[i]], 1);
}

__global__ void k_scan1(const int* __restrict__ deg, int n, int* __restrict__ off,
                        int* __restrict__ bsum) {
    __shared__ int sh[1024];
    int tid = threadIdx.x, i = blockIdx.x * 1024 + tid;
    int v = (i < n) ? deg[i] : 0;
    sh[tid] = v;
    __syncthreads();
    for (int s = 1; s < 1024; s <<= 1) {
        int t = (tid >= s) ? sh[tid - s] : 0;
        __syncthreads();
        sh[tid] += t;
        __syncthreads();
    }
    if (i < n) off[i] = sh[tid] - v;       // block-local exclusive
    if (tid == 1023) bsum[blockIdx.x] = sh[tid];
}

__global__ void k_scan2(int* __restrict__ bsum, int nb, int* __restrict__ off, int n) {
    int tid = threadIdx.x;                  // 64 threads, nb <= 64
    int v = (tid < nb) ? bsum[tid] : 0;
    int incl = v;
    for (int s = 1; s < 64; s <<= 1) {
        int t = __shfl_up(incl, s);
        if (tid >= s) incl += t;
    }
    if (tid < nb) bsum[tid] = incl - v;     // exclusive block offsets
    if (tid == 63) off[n] = incl;           // grand total
}

__global__ void k_scan3(int* __restrict__ off, const int* __restrict__ bsum, int n,
                        int* __restrict__ cur) {
    int i = blockIdx.x * 1024 + threadIdx.x;
    if (i < n) {
        int v = off[i] + bsum[blockIdx.x];
        off[i] = v;
        cur[i] = v;
    }
}

__global__ void k_fill(const int* __restrict__ src, const int* __restrict__ dst, int E,
                       int* __restrict__ cur, int* __restrict__ csr) {
    int i = blockIdx.x * blockDim.x + threadIdx.x;
    if (i < E) {
        int p = atomicAdd(&cur[dst[i]], 1);
        csr[p] = src[i];
    }
}

// ---- softmax + aggregation, one wave per node; bf16 features in, bf16 out ----
__global__ void k_agg(const unsigned short* __restrict__ fb, const float4* __restrict__ el4,
                      const float* __restrict__ er4, const int* __restrict__ off,
                      const int* __restrict__ csr, const void* __restrict__ bias,
                      unsigned short* __restrict__ outb, int Nn, const int* __restrict__ flag) {
    int lane = threadIdx.x & 63;
    int n = blockIdx.x * (blockDim.x >> 6) + (threadIdx.x >> 6);
    if (n >= Nn) return;
    int isb = *flag;
    int s0 = off[n], s1 = off[n + 1];
    int deg = s1 - s0;
    float er0 = er4[n * 4 + 0], er1 = er4[n * 4 + 1], er2 = er4[n * 4 + 2];
    float a0 = 0.f, a1 = 0.f, a2 = 0.f;

    if (deg > 0 && deg <= 64) {
        int e = s0 + lane;
        bool on = e < s1;
        int sIdx = on ? csr[e] : 0;
        float4 el = el4[sIdx];
        float t0 = on ? lrelu(el.x + er0) : -1e30f;
        float t1 = on ? lrelu(el.y + er1) : -1e30f;
        float t2 = on ? lrelu(el.z + er2) : -1e30f;
        float m0 = t0, m1 = t1, m2 = t2;
        for (int d = 1; d < 64; d <<= 1) {
            m0 = fmaxf(m0, __shfl_xor(m0, d));
            m1 = fmaxf(m1, __shfl_xor(m1, d));
            m2 = fmaxf(m2, __shfl_xor(m2, d));
        }
        float w0 = on ? __expf(t0 - m0) : 0.f;
        float w1 = on ? __expf(t1 - m1) : 0.f;
        float w2 = on ? __expf(t2 - m2) : 0.f;
        float d0 = w0, d1 = w1, d2 = w2;
        for (int d = 1; d < 64; d <<= 1) {
            d0 += __shfl_xor(d0, d);
            d1 += __shfl_xor(d1, d);
            d2 += __shfl_xor(d2, d);
        }
        w0 *= 1.f / d0; w1 *= 1.f / d1; w2 *= 1.f / d2;
#pragma unroll 4
        for (int j = 0; j < deg; ++j) {
            int s = __shfl(sIdx, j);
            float u0 = __shfl(w0, j), u1 = __shfl(w1, j), u2 = __shfl(w2, j);
            const unsigned short* fr = fb + (long)s * HD;
            a0 += u0 * b2f(fr[lane]);
            a1 += u1 * b2f(fr[lane + 64]);
            a2 += u2 * b2f(fr[lane + 128]);
        }
    } else if (deg > 64) {
        float m0 = -1e30f, m1 = -1e30f, m2 = -1e30f;
        for (int e = s0 + lane; e < s1; e += 64) {
            float4 el = el4[csr[e]];
            m0 = fmaxf(m0, lrelu(el.x + er0));
            m1 = fmaxf(m1, lrelu(el.y + er1));
            m2 = fmaxf(m2, lrelu(el.z + er2));
        }
        for (int d = 1; d < 64; d <<= 1) {
            m0 = fmaxf(m0, __shfl_xor(m0, d));
            m1 = fmaxf(m1, __shfl_xor(m1, d));
            m2 = fmaxf(m2, __shfl_xor(m2, d));
        }
        float d0 = 0.f, d1 = 0.f, d2 = 0.f;
        for (int e = s0 + lane; e < s1; e += 64) {
            float4 el = el4[csr[e]];
            d0 += __expf(lrelu(el.x + er0) - m0);
            d1 += __expf(lrelu(el.y + er1) - m1);
            d2 += __expf(lrelu(el.z + er2) - m2);
        }
        for (int d = 1; d < 64; d <<= 1) {
            d0 += __shfl_xor(d0, d);
            d1 += __shfl_xor(d1, d);
            d2 += __shfl_xor(d2, d);
        }
        float id0 = 1.f / d0, id1 = 1.f / d1, id2 = 1.f / d2;
        for (int e = s0; e < s1; ++e) {
            int s = csr[e];
            float4 el = el4[s];
            float w0 = __expf(lrelu(el.x + er0) - m0) * id0;
            float w1 = __expf(lrelu(el.y + er1) - m1) * id1;
            float w2 = __expf(lrelu(el.z + er2) - m2) * id2;
            const unsigned short* fr = fb + (long)s * HD;
            a0 += w0 * b2f(fr[lane]);
            a1 += w1 * b2f(fr[lane + 64]);
            a2 += w2 * b2f(fr[lane + 128]);
        }
    }
    a0 = fmaxf(a0 + gload(bias, lane,       isb), 0.f);
    a1 = fmaxf(a1 + gload(bias, lane + 64,  isb), 0.f);
    a2 = fmaxf(a2 + gload(bias, lane + 128, isb), 0.f);
    unsigned short* brow = outb + (long)n * HD;
    brow[lane]       = f2b(a0);
    brow[lane + 64]  = f2b(a1);
    brow[lane + 128] = f2b(a2);
}

// ---- per-edge score with LDS-staged coalesced writes ----
// block = 256 threads = 256 edges; stage scores in LDS, stream out as uint4.
__global__ void k_score(const int* __restrict__ src, const int* __restrict__ dst,
                        const float* __restrict__ PQ, const void* __restrict__ bp,
                        void* __restrict__ out, int E, const int* __restrict__ flag) {
    __shared__ float sh[256 * NC];            // 10 KB
    int tid = threadIdx.x;
    int e0 = blockIdx.x * 256;
    int e = e0 + tid;
    int isb = *flag;
    float v[NC];
    if (e < E) {
        const float* pr = PQ + (long)src[e] * (2 * NC);
        const float* qr = PQ + (long)dst[e] * (2 * NC) + NC;
#pragma unroll
        for (int c = 0; c < NC; ++c) v[c] = pr[c] + qr[c] + gload(bp, c, isb);
    }
    int nE = min(256, E - e0);
    if (isb) {
        unsigned int* shu = (unsigned int*)sh;
        if (e < E) {
#pragma unroll
            for (int c = 0; c < NC / 2; ++c)
                shu[tid * (NC / 2) + c] =
                    (unsigned)f2b(v[2 * c]) | ((unsigned)f2b(v[2 * c + 1]) << 16);
        }
        __syncthreads();
        int nU = nE * (NC / 2);               // uints to write (1280 for full block)
        unsigned int* ob = (unsigned int*)((unsigned short*)out + (long)e0 * NC);
        int nU4 = nU >> 2;
        uint4* ob4 = (uint4*)ob;
        const uint4* sb4 = (const uint4*)shu;
        for (int u = tid; u < nU4; u += 256) ob4[u] = sb4[u];
        for (int w = (nU4 << 2) + tid; w < nU; w += 256) ob[w] = shu[w];
    } else {
        if (e < E) {
#pragma unroll
            for (int c = 0; c < NC; ++c) sh[tid * NC + c] = v[c];
        }
        __syncthreads();
        int nU = nE * NC;                      // floats to write (2560 for full block)
        float* ob = (float*)out + (long)e0 * NC;
        int nU4 = nU >> 2;
        float4* ob4 = (float4*)ob;
        const float4* sb4 = (const float4*)sh;
        for (int u = tid; u < nU4; u += 256) ob4[u] = sb4[u];
        for (int w = (nU4 << 2) + tid; w < nU; w += 256) ob[w] = sh[w];
    }
}

extern "C" void kernel_launch(void* const* d_in, const int* in_sizes, int n_in,
                              void* d_out, int out_size, void* d_ws, size_t ws_size,
                              hipStream_t stream) {
    const int* src = (const int*)d_in[0];
    const int* dst = (const int*)d_in[1];
    const void* nfeats = d_in[2];
    // d_in[3] = efeats, unused
    const void* W1  = d_in[4];
    const void* al1 = d_in[5];
    const void* ar1 = d_in[6];
    const void* b1  = d_in[7];
    const void* W2  = d_in[8];
    const void* al2 = d_in[9];
    const void* ar2 = d_in[10];
    const void* b2  = d_in[11];
    const void* Wp  = d_in[12];
    const void* bp  = d_in[13];

    const int E = in_sizes[0];
    const int N = in_sizes[2] / KIN;

    // workspace layout (256B aligned), ~60 MB
    size_t o = 0;
    auto alloc = [&](size_t bytes) { size_t r = o; o = (o + bytes + 255) & ~(size_t)255; return r; };
    char* ws = (char*)d_ws;
    int*   flag = (int*)  (ws + alloc(4));
    int*   deg  = (int*)  (ws + alloc((size_t)N * 4));
    int*   off  = (int*)  (ws + alloc((size_t)(N + 1) * 4));
    int*   cur  = (int*)  (ws + alloc((size_t)N * 4));
    int*   bsum = (int*)  (ws + alloc(64 * 4));
    int*   csr  = (int*)  (ws + alloc((size_t)E * 4));
    unsigned short* xb  = (unsigned short*)(ws + alloc((size_t)N * KIN * 2));
    unsigned short* fb  = (unsigned short*)(ws + alloc((size_t)N * HD * 2));
    unsigned short* hb  = (unsigned short*)(ws + alloc((size_t)N * HD * 2));
    unsigned short* Bp1 = (unsigned short*)(ws + alloc((size_t)12 * 4 * 512 * 2));
    unsigned short* Bp2 = (unsigned short*)(ws + alloc((size_t)12 * 6 * 512 * 2));
    unsigned short* BpPQ= (unsigned short*)(ws + alloc((size_t)2 * 6 * 512 * 2));
    float* el4  = (float*)(ws + alloc((size_t)N * 16));
    float* er4  = (float*)(ws + alloc((size_t)N * 16));
    float* PQ   = (float*)(ws + alloc((size_t)N * 2 * NC * 4));
    (void)ws_size; (void)n_in; (void)out_size;

    const int TB = 256;
    int gE   = (E + TB - 1) / TB;
    int gN   = (N + TB - 1) / TB;
    int gAgg = (N + 3) / 4;                    // 4 waves (nodes) per block
    int rowTiles = (N + 15) / 16;              // 3125
    int gMM  = (rowTiles + 3) / 4;
    int nb   = (N + 1023) / 1024;              // scan blocks (<= 64)

    k_probe<<<1, 64, 0, stream>>>(W1, flag);

    // staging: bf16 A input + fragment-packed B matrices
    long nx = (long)N * KIN;
    k_cvt<<<(int)((nx + TB - 1) / TB), TB, 0, stream>>>(nfeats, xb, nx, flag);
    k_pack<<<(12 * 4 * 512 + TB - 1) / TB, TB, 0, stream>>>(W1, Bp1, KIN, HD, 12, 4, 0, flag);
    k_pack<<<(12 * 6 * 512 + TB - 1) / TB, TB, 0, stream>>>(W2, Bp2, HD, HD, 12, 6, 0, flag);
    k_pack<<<(6 * 512 + TB - 1) / TB, TB, 0, stream>>>(Wp, BpPQ,            HD, NC, 1, 6, 0,  flag);
    k_pack<<<(6 * 512 + TB - 1) / TB, TB, 0, stream>>>(Wp, BpPQ + 6 * 512,  HD, NC, 1, 6, HD, flag);

    // CSR build (dst-indexed), hierarchical scan
    k_zero<<<gN, TB, 0, stream>>>(deg, N);
    k_hist<<<gE, TB, 0, stream>>>(dst, E, deg);
    k_scan1<<<nb, 1024, 0, stream>>>(deg, N, off, bsum);
    k_scan2<<<1, 64, 0, stream>>>(bsum, nb, off, N);
    k_scan3<<<nb, 1024, 0, stream>>>(off, bsum, N, cur);
    k_fill<<<gE, TB, 0, stream>>>(src, dst, E, cur, csr);

    // layer 1: fused gemm+el/er, then softmax-aggregate
    k_mm<12, 4, 1><<<gMM, TB, 0, stream>>>(xb, Bp1, fb, al1, ar1, el4, er4, N, HD, flag);
    k_agg<<<gAgg, TB, 0, stream>>>(fb, (const float4*)el4, er4, off, csr, b1, hb, N, flag);

    // layer 2
    k_mm<12, 6, 1><<<gMM, TB, 0, stream>>>(hb, Bp2, fb, al2, ar2, el4, er4, N, HD, flag);
    k_agg<<<gAgg, TB, 0, stream>>>(fb, (const float4*)el4, er4, off, csr, b2, hb, N, flag);

    // predictor
    k_mmpq<<<gMM, TB, 0, stream>>>(hb, BpPQ, PQ, N);
    k_score<<<gE, TB, 0, stream>>>(src, dst, PQ, bp, d_out, E, flag);
}